// Round 13
// baseline (53.185 us; speedup 1.0000x reference)
//
#include <hip/hip_runtime.h>
#include <hip/hip_bf16.h>

typedef __bf16 bf16x8 __attribute__((ext_vector_type(8)));
typedef float f32x4 __attribute__((ext_vector_type(4)));

#define G 8
#define B 32
#define D 32
#define O 32
#define K 4096   // N*T (floats per W row)
#define T 64
#define KSPLIT 2
#define KCHUNK (K / KSPLIT)   // 2048 floats
#define BK 256                // floats staged per row per step (1KB burst)
#define NSTEP (KCHUNK / BK)   // 8
#define MROWS 16              // o-rows per block

// ws: [0,256KB) XB bf16; [4MB, 8MB) probe scratch (4MB floats).
#define XB_ELEMS (B * K)
#define PROBE_THREADS (4096 * 256)   // 1,048,576 -> 8 float4 each = 128 MB

// MEASUREMENT PROBE: pure-read ceiling reference. Grid-stride, fully
// coalesced float4 loads of all of W; 16 waves/CU; 8 independent loads in
// flight per thread; per-thread sum written coalesced (keeps loads live).
__global__ __launch_bounds__(256) void probe_read(const f32x4* __restrict__ W4,
                                                  float* __restrict__ scratch) {
    const int tid = blockIdx.x * 256 + threadIdx.x;
    f32x4 a0 = W4[tid];
    f32x4 a1 = W4[tid + (size_t)PROBE_THREADS];
    f32x4 a2 = W4[tid + (size_t)2 * PROBE_THREADS];
    f32x4 a3 = W4[tid + (size_t)3 * PROBE_THREADS];
    f32x4 a4 = W4[tid + (size_t)4 * PROBE_THREADS];
    f32x4 a5 = W4[tid + (size_t)5 * PROBE_THREADS];
    f32x4 a6 = W4[tid + (size_t)6 * PROBE_THREADS];
    f32x4 a7 = W4[tid + (size_t)7 * PROBE_THREADS];
    f32x4 s = a0 + a1 + a2 + a3 + a4 + a5 + a6 + a7;
    scratch[tid] = s[0] + s[1] + s[2] + s[3];
}

// Fused prep: threads [0,16384) build XB (MFMA B-frag order, no mask);
// threads [16384, 49152) init out[b][d][o] = bias[d][o] (gemm atomically adds).
__global__ __launch_bounds__(256) void prep_and_init(const float* __restrict__ x,
                                                     const float* __restrict__ bias,
                                                     __bf16* __restrict__ xb,
                                                     float* __restrict__ out) {
    int tid = blockIdx.x * 256 + threadIdx.x;
    if (tid < 16384) {
        int b = (tid >> 2) & 31;
        int k = (tid >> 7) * 32 + (tid & 3) * 8;
        const float4 x0 = *(const float4*)(x + b * K + k);
        const float4 x1 = *(const float4*)(x + b * K + k + 4);
        bf16x8 r;
        r[0] = (__bf16)x0.x; r[1] = (__bf16)x0.y; r[2] = (__bf16)x0.z; r[3] = (__bf16)x0.w;
        r[4] = (__bf16)x1.x; r[5] = (__bf16)x1.y; r[6] = (__bf16)x1.z; r[7] = (__bf16)x1.w;
        *(bf16x8*)(xb + (size_t)tid * 8) = r;   // flat idx == tid*8: coalesced
    } else {
        int t2 = tid - 16384;           // 32768 = B*D*O, out flat = b*1024 + d*32 + o
        out[t2] = bias[t2 & 1023];
    }
}

// R8 gemm, verbatim (best: 35.2us total). Block (d, g, oh, ks); 2 waves;
// global_load_lds 1KB bursts; XOR swizzle both sides; mask on A-fragment;
// 4 blocks/CU; fused y-weighted atomic epilogue.
__global__ __launch_bounds__(128) void gemm_main(const float* __restrict__ W,
                                                 const __bf16* __restrict__ xb,
                                                 const float* __restrict__ mask,
                                                 const float* __restrict__ y,
                                                 float* __restrict__ out) {
    __shared__ float ldsW[2][MROWS * BK];   // 2 x 16 KB
    const int d = blockIdx.x, g = blockIdx.y;
    const int oh = blockIdx.z & 1, ks = blockIdx.z >> 1;
    const int wid  = threadIdx.x >> 6;      // 0..1 = bh
    const int lane = threadIdx.x & 63;
    const int bh = wid;
    const int l15 = lane & 15, g16 = lane >> 4;

    const int lds_ro = l15 * 1024 + ((g16 * 32) ^ ((l15 & 7) * 16));

    const float* mrow = mask + (oh * 16 + l15) * T + g16 * 8;
    const float4 me0 = *(const float4*)(mrow);
    const float4 me1 = *(const float4*)(mrow + 4);
    const float4 mo0 = *(const float4*)(mrow + 32);
    const float4 mo1 = *(const float4*)(mrow + 36);

    const __bf16* xbl = xb + (size_t)(ks * (KCHUNK / 32)) * 1024
                           + (bh * 16 + l15) * 32 + g16 * 8;

    const size_t wrow0 = ((size_t)(g * D + d) * O + oh * 16 + 8 * wid) * K
                         + (size_t)ks * KCHUNK;

    f32x4 acc = {0.f, 0.f, 0.f, 0.f};

#define STAGE(buf, step)                                                          \
    {                                                                             \
        _Pragma("unroll")                                                         \
        for (int i = 0; i < 8; ++i) {                                             \
            const int row = 8 * wid + i;                                          \
            const char* src = (const char*)(W + wrow0 + (size_t)i * K             \
                                            + (size_t)(step) * BK)                \
                              + ((lane * 16) ^ (i * 16));                         \
            __builtin_amdgcn_global_load_lds(                                     \
                (const __attribute__((address_space(1))) void*)src,               \
                (__attribute__((address_space(3))) void*)((char*)&ldsW[buf][0]    \
                                                          + row * 1024),          \
                16, 0, 0);                                                        \
        }                                                                         \
    }

    STAGE(0, 0);
    __syncthreads();

    int cur = 0;
    for (int step = 0; step < NSTEP; ++step) {
        if (step + 1 < NSTEP) STAGE(cur ^ 1, step + 1);

        const char* lb = (const char*)&ldsW[cur][0];
        const __bf16* xs = xbl + (size_t)(step * 8) * 1024;
        #pragma unroll
        for (int s = 0; s < 8; ++s) {
            const int a0 = lds_ro + s * 128;
            const f32x4 alo = *(const f32x4*)(lb + a0);
            const f32x4 ahi = *(const f32x4*)(lb + (a0 ^ 16));
            const float4 ms0 = (s & 1) ? mo0 : me0;
            const float4 ms1 = (s & 1) ? mo1 : me1;
            bf16x8 af;
            af[0] = (__bf16)(alo[0] * ms0.x); af[1] = (__bf16)(alo[1] * ms0.y);
            af[2] = (__bf16)(alo[2] * ms0.z); af[3] = (__bf16)(alo[3] * ms0.w);
            af[4] = (__bf16)(ahi[0] * ms1.x); af[5] = (__bf16)(ahi[1] * ms1.y);
            af[6] = (__bf16)(ahi[2] * ms1.z); af[7] = (__bf16)(ahi[3] * ms1.w);
            const bf16x8 bfr = *(const bf16x8*)(xs + (size_t)s * 1024);
            acc = __builtin_amdgcn_mfma_f32_16x16x32_bf16(af, bfr, acc, 0, 0, 0);
        }
        __syncthreads();
        cur ^= 1;
    }
#undef STAGE

    const int bg = bh * 16 + l15;                 // global b
    const float yv = y[bg * G + g];
    float* op = out + bg * (D * O) + d * O + oh * 16;
    #pragma unroll
    for (int i = 0; i < 4; ++i)
        unsafeAtomicAdd(op + g16 * 4 + i, yv * acc[i]);
}

extern "C" void kernel_launch(void* const* d_in, const int* in_sizes, int n_in,
                              void* d_out, int out_size, void* d_ws, size_t ws_size,
                              hipStream_t stream) {
    const float* x    = (const float*)d_in[0];
    const float* y    = (const float*)d_in[1];
    const float* w    = (const float*)d_in[2];
    const float* bias = (const float*)d_in[3];
    const float* mask = (const float*)d_in[4];
    float* out = (float*)d_out;

    __bf16* xbp    = (__bf16*)d_ws;
    float*  probes = (float*)((char*)d_ws + (4u << 20));   // [4MB, 8MB)

    probe_read<<<4096, 256, 0, stream>>>((const f32x4*)w, probes);
    prep_and_init<<<192, 256, 0, stream>>>(x, bias, xbp, out);
    gemm_main<<<dim3(D, G, 4), 128, 0, stream>>>(w, xbp, mask, y, out);
}

// Round 14
// 49.096 us; speedup vs baseline: 1.0833x; 1.0833x over previous
//
#include <hip/hip_runtime.h>
#include <hip/hip_bf16.h>

typedef __bf16 bf16x8 __attribute__((ext_vector_type(8)));
typedef float f32x4 __attribute__((ext_vector_type(4)));

#define G 8
#define B 32
#define D 32
#define O 32
#define K 4096   // N*T (floats per W row)
#define T 64
#define KSPLIT 4
#define KCHUNK (K / KSPLIT)   // 1024 floats
#define BK 256                // floats staged per row per step (1KB burst)
#define NSTEP (KCHUNK / BK)   // 4
#define MROWS 32              // o-rows per block (FULL o range)

// ws: XB bf16 [K/32][B][32] = 256 KB only.
#define XB_ELEMS (B * K)

// Fused prep: threads [0,16384) build XB (MFMA B-frag order, no mask);
// threads [16384, 49152) init out[b][d][o] = bias[d][o] (gemm atomically adds).
__global__ __launch_bounds__(256) void prep_and_init(const float* __restrict__ x,
                                                     const float* __restrict__ bias,
                                                     __bf16* __restrict__ xb,
                                                     float* __restrict__ out) {
    int tid = blockIdx.x * 256 + threadIdx.x;
    if (tid < 16384) {
        int b = (tid >> 2) & 31;
        int k = (tid >> 7) * 32 + (tid & 3) * 8;
        const float4 x0 = *(const float4*)(x + b * K + k);
        const float4 x1 = *(const float4*)(x + b * K + k + 4);
        bf16x8 r;
        r[0] = (__bf16)x0.x; r[1] = (__bf16)x0.y; r[2] = (__bf16)x0.z; r[3] = (__bf16)x0.w;
        r[4] = (__bf16)x1.x; r[5] = (__bf16)x1.y; r[6] = (__bf16)x1.z; r[7] = (__bf16)x1.w;
        *(bf16x8*)(xb + (size_t)tid * 8) = r;   // flat idx == tid*8: coalesced
    } else {
        int t2 = tid - 16384;           // 32768 = B*D*O, out flat = b*1024 + d*32 + o
        out[t2] = bias[t2 & 1023];
    }
}

// Block (d, g, ks): M = ALL 32 o-rows (contiguous in W for fixed g,d),
// N = 32 b, K-quarter ks. 128 threads = 2 waves; wave bh owns b-half.
// Each wave computes 32o x 16b: per k-tile TWO MFMAs (o-lo rows 0-15 via accL,
// o-hi rows 16-31 via accH) SHARING one xb B-fragment -- this halves xb
// global traffic vs R8 (xb total 128MB -> 64MB; combined 256 -> 192MB, the
// measured load-path ceiling being ~8.5 TB/s combined; W+xb were 1:1 before).
// W staged via global_load_lds, 1KB contiguous burst per o-row per step;
// XOR chunk-swizzle (row&7)<<4 on source AND lds-read addrs (rule 21).
// mask[o][t] applied to the A-fragment before bf16 convert (m_lo/m_hi sets).
// LDS 2x32KB dbuf -> 2 independent blocks/CU.
// Epilogue: out[b][d][o] += y[b][g] * acc  (unsafeAtomicAdd).
__global__ __launch_bounds__(128) void gemm_main(const float* __restrict__ W,
                                                 const __bf16* __restrict__ xb,
                                                 const float* __restrict__ mask,
                                                 const float* __restrict__ y,
                                                 float* __restrict__ out) {
    __shared__ float ldsW[2][MROWS * BK];   // 2 x 32 KB
    const int d = blockIdx.x, g = blockIdx.y, ks = blockIdx.z;
    const int wid  = threadIdx.x >> 6;      // 0..1 = bh
    const int lane = threadIdx.x & 63;
    const int bh = wid;
    const int l15 = lane & 15, g16 = lane >> 4;

    // A-fragment reads: o-lo row = l15, o-hi row = 16+l15 (same XOR since
    // (16+l15)&7 == l15&7); byte = s*128 + g16*32 (^16 for hi half), swizzled
    const int lds_lo = l15 * 1024 + ((g16 * 32) ^ ((l15 & 7) * 16));
    const int lds_hi = lds_lo + 16 * 1024;

    // mask rows: o = l15 (lo) and 16+l15 (hi); lane needs t = (s&1)*32 + g16*8 + j
    const float* mlo = mask + l15 * T + g16 * 8;
    const float4 le0 = *(const float4*)(mlo);
    const float4 le1 = *(const float4*)(mlo + 4);
    const float4 lo0 = *(const float4*)(mlo + 32);
    const float4 lo1 = *(const float4*)(mlo + 36);
    const float* mhi = mask + (16 + l15) * T + g16 * 8;
    const float4 he0 = *(const float4*)(mhi);
    const float4 he1 = *(const float4*)(mhi + 4);
    const float4 ho0 = *(const float4*)(mhi + 32);
    const float4 ho1 = *(const float4*)(mhi + 36);

    // XB: k-tile kt = ks*32 + step*8 + s; elem = kt*1024 + b*32 + g16*8
    const __bf16* xbl = xb + (size_t)(ks * (KCHUNK / 32)) * 1024
                           + (bh * 16 + l15) * 32 + g16 * 8;

    // staging: wave wid stages rows 16*wid .. 16*wid+15 (contiguous in W)
    const size_t wrow0 = ((size_t)(g * D + d) * O + 16 * wid) * K
                         + (size_t)ks * KCHUNK;

    f32x4 accL = {0.f, 0.f, 0.f, 0.f};
    f32x4 accH = {0.f, 0.f, 0.f, 0.f};

#define STAGE(buf, step)                                                          \
    {                                                                             \
        _Pragma("unroll")                                                         \
        for (int i = 0; i < 16; ++i) {                                            \
            const int row = 16 * wid + i;                                         \
            const char* src = (const char*)(W + wrow0 + (size_t)i * K             \
                                            + (size_t)(step) * BK)                \
                              + ((lane * 16) ^ ((i & 7) * 16));                   \
            __builtin_amdgcn_global_load_lds(                                     \
                (const __attribute__((address_space(1))) void*)src,               \
                (__attribute__((address_space(3))) void*)((char*)&ldsW[buf][0]    \
                                                          + row * 1024),          \
                16, 0, 0);                                                        \
        }                                                                         \
    }

    STAGE(0, 0);
    __syncthreads();

    int cur = 0;
    for (int step = 0; step < NSTEP; ++step) {
        if (step + 1 < NSTEP) STAGE(cur ^ 1, step + 1);

        const char* lb = (const char*)&ldsW[cur][0];
        const __bf16* xs = xbl + (size_t)(step * 8) * 1024;
        #pragma unroll
        for (int s = 0; s < 8; ++s) {
            const bf16x8 bfr = *(const bf16x8*)(xs + (size_t)s * 1024);

            // o-lo fragment
            {
                const int a0 = lds_lo + s * 128;
                const f32x4 alo = *(const f32x4*)(lb + a0);
                const f32x4 ahi = *(const f32x4*)(lb + (a0 ^ 16));
                const float4 ms0 = (s & 1) ? lo0 : le0;
                const float4 ms1 = (s & 1) ? lo1 : le1;
                bf16x8 af;
                af[0] = (__bf16)(alo[0] * ms0.x); af[1] = (__bf16)(alo[1] * ms0.y);
                af[2] = (__bf16)(alo[2] * ms0.z); af[3] = (__bf16)(alo[3] * ms0.w);
                af[4] = (__bf16)(ahi[0] * ms1.x); af[5] = (__bf16)(ahi[1] * ms1.y);
                af[6] = (__bf16)(ahi[2] * ms1.z); af[7] = (__bf16)(ahi[3] * ms1.w);
                accL = __builtin_amdgcn_mfma_f32_16x16x32_bf16(af, bfr, accL, 0, 0, 0);
            }
            // o-hi fragment (same xb fragment bfr -- the dedup)
            {
                const int a0 = lds_hi + s * 128;
                const f32x4 alo = *(const f32x4*)(lb + a0);
                const f32x4 ahi = *(const f32x4*)(lb + (a0 ^ 16));
                const float4 ms0 = (s & 1) ? ho0 : he0;
                const float4 ms1 = (s & 1) ? ho1 : he1;
                bf16x8 af;
                af[0] = (__bf16)(alo[0] * ms0.x); af[1] = (__bf16)(alo[1] * ms0.y);
                af[2] = (__bf16)(alo[2] * ms0.z); af[3] = (__bf16)(alo[3] * ms0.w);
                af[4] = (__bf16)(ahi[0] * ms1.x); af[5] = (__bf16)(ahi[1] * ms1.y);
                af[6] = (__bf16)(ahi[2] * ms1.z); af[7] = (__bf16)(ahi[3] * ms1.w);
                accH = __builtin_amdgcn_mfma_f32_16x16x32_bf16(af, bfr, accH, 0, 0, 0);
            }
        }
        __syncthreads();
        cur ^= 1;
    }
#undef STAGE

    // C/D: lane holds D[row=g16*4+i][col=l15]; accL -> o rows 0-15, accH -> 16-31
    const int bg = bh * 16 + l15;                 // global b
    const float yv = y[bg * G + g];
    float* op = out + bg * (D * O) + d * O;
    #pragma unroll
    for (int i = 0; i < 4; ++i) {
        unsafeAtomicAdd(op + g16 * 4 + i,      yv * accL[i]);
        unsafeAtomicAdd(op + 16 + g16 * 4 + i, yv * accH[i]);
    }
}

extern "C" void kernel_launch(void* const* d_in, const int* in_sizes, int n_in,
                              void* d_out, int out_size, void* d_ws, size_t ws_size,
                              hipStream_t stream) {
    const float* x    = (const float*)d_in[0];
    const float* y    = (const float*)d_in[1];
    const float* w    = (const float*)d_in[2];
    const float* bias = (const float*)d_in[3];
    const float* mask = (const float*)d_in[4];
    float* out = (float*)d_out;

    __bf16* xbp = (__bf16*)d_ws;

    prep_and_init<<<192, 256, 0, stream>>>(x, bias, xbp, out);
    gemm_main<<<dim3(D, G, KSPLIT), 128, 0, stream>>>(w, xbp, mask, y, out);
}

// Round 15
// 43.734 us; speedup vs baseline: 1.2161x; 1.1226x over previous
//
#include <hip/hip_runtime.h>
#include <hip/hip_bf16.h>

typedef __bf16 bf16x8 __attribute__((ext_vector_type(8)));
typedef float f32x4 __attribute__((ext_vector_type(4)));

#define G 8
#define B 32
#define D 32
#define O 32
#define K 4096   // N*T (floats per W row)
#define T 64
#define KSPLIT 2
#define KCHUNK (K / KSPLIT)   // 2048 floats
#define BK 256                // floats staged per row per step (1KB/row)
#define NSTEP (KCHUNK / BK)   // 8
#define MROWS 16              // o-rows per block

// ws: XB bf16 [K/32][B][32] = 256 KB only.
#define XB_ELEMS (B * K)

// Fused prep: threads [0,16384) build XB (MFMA B-frag order, no mask);
// threads [16384, 49152) init out[b][d][o] = bias[d][o] (gemm atomically adds).
__global__ __launch_bounds__(256) void prep_and_init(const float* __restrict__ x,
                                                     const float* __restrict__ bias,
                                                     __bf16* __restrict__ xb,
                                                     float* __restrict__ out) {
    int tid = blockIdx.x * 256 + threadIdx.x;
    if (tid < 16384) {
        int b = (tid >> 2) & 31;
        int k = (tid >> 7) * 32 + (tid & 3) * 8;
        const float4 x0 = *(const float4*)(x + b * K + k);
        const float4 x1 = *(const float4*)(x + b * K + k + 4);
        bf16x8 r;
        r[0] = (__bf16)x0.x; r[1] = (__bf16)x0.y; r[2] = (__bf16)x0.z; r[3] = (__bf16)x0.w;
        r[4] = (__bf16)x1.x; r[5] = (__bf16)x1.y; r[6] = (__bf16)x1.z; r[7] = (__bf16)x1.w;
        *(bf16x8*)(xb + (size_t)tid * 8) = r;   // flat idx == tid*8: coalesced
    } else {
        int t2 = tid - 16384;           // 32768 = B*D*O, out flat = b*1024 + d*32 + o
        out[t2] = bias[t2 & 1023];
    }
}

// Block (d, g, oh, ks): R8 consumer skeleton (M=16 o-rows, N=32 b, 2 waves,
// 8 k-tiles/step, XOR swizzle, mask-on-A, atomic epilogue), but W staging is
// REGISTER-staged with a 3-set ring: step t issues plain global_load_dwordx4
// for step t+3 (8 rows x 1KB per wave), computes step t, then ds_writes step
// t+1's set into the spare LDS buffer. The only stall is the compiler's
// vmcnt wait on data issued 2.5 steps earlier; raw s_barrier + lgkmcnt(0)
// (NOT __syncthreads = vmcnt(0) drain) keeps 16-24KB/wave of W loads in
// flight at all times -> ~128-192KB/CU (Little's law: the R8 cap was 64KB).
__global__ __launch_bounds__(128, 2) void gemm_main(const float* __restrict__ W,
                                                    const __bf16* __restrict__ xb,
                                                    const float* __restrict__ mask,
                                                    const float* __restrict__ y,
                                                    float* __restrict__ out) {
    __shared__ float ldsW[2][MROWS * BK];   // 2 x 16 KB
    const int d = blockIdx.x, g = blockIdx.y;
    const int oh = blockIdx.z & 1, ks = blockIdx.z >> 1;
    const int wid  = threadIdx.x >> 6;      // 0..1 = bh
    const int lane = threadIdx.x & 63;
    const int bh = wid;
    const int l15 = lane & 15, g16 = lane >> 4;

    // A-fragment: local row = l15, byte = s*128 + g16*32 (^16 hi), swizzled
    const int lds_ro = l15 * 1024 + ((g16 * 32) ^ ((l15 & 7) * 16));

    // mask row o = oh*16 + l15; lane needs t = (s&1)*32 + g16*8 + j
    const float* mrow = mask + (oh * 16 + l15) * T + g16 * 8;
    const float4 me0 = *(const float4*)(mrow);
    const float4 me1 = *(const float4*)(mrow + 4);
    const float4 mo0 = *(const float4*)(mrow + 32);
    const float4 mo1 = *(const float4*)(mrow + 36);

    // XB: k-tile kt = ks*64 + step*8 + s; elem = kt*1024 + b*32 + g16*8
    const __bf16* xbl = xb + (size_t)(ks * (KCHUNK / 32)) * 1024
                           + (bh * 16 + l15) * 32 + g16 * 8;

    // staging: wave wid owns local rows 8*wid .. 8*wid+7
    const size_t wrow0 = ((size_t)(g * D + d) * O + oh * 16 + 8 * wid) * K
                         + (size_t)ks * KCHUNK;

    f32x4 acc = {0.f, 0.f, 0.f, 0.f};
    f32x4 rg[3][8];   // 3-deep W prefetch ring (96 VGPR); all indices static

#define RELOAD(sA, stepn)                                                         \
    {                                                                             \
        _Pragma("unroll")                                                         \
        for (int i = 0; i < 8; ++i)                                               \
            rg[sA][i] = *(const f32x4*)(W + wrow0 + (size_t)i * K                 \
                                        + (stepn) * BK + lane * 4);               \
    }
#define DSWRITE(buf, sB)                                                          \
    {                                                                             \
        _Pragma("unroll")                                                         \
        for (int i = 0; i < 8; ++i) {                                             \
            const int row = 8 * wid + i;                                          \
            *(f32x4*)((char*)&ldsW[buf][0] + row * 1024                           \
                      + ((lane * 16) ^ (i * 16))) = rg[sB][i];                    \
        }                                                                         \
    }
#define COMPUTE(t)                                                                \
    {                                                                             \
        const char* lb = (const char*)&ldsW[(t) & 1][0];                          \
        const __bf16* xs = xbl + (size_t)((t) * 8) * 1024;                        \
        _Pragma("unroll")                                                         \
        for (int s = 0; s < 8; ++s) {                                             \
            const int a0 = lds_ro + s * 128;                                      \
            const f32x4 alo = *(const f32x4*)(lb + a0);                           \
            const f32x4 ahi = *(const f32x4*)(lb + (a0 ^ 16));                    \
            const float4 ms0 = (s & 1) ? mo0 : me0;                               \
            const float4 ms1 = (s & 1) ? mo1 : me1;                               \
            bf16x8 af;                                                            \
            af[0] = (__bf16)(alo[0] * ms0.x); af[1] = (__bf16)(alo[1] * ms0.y);   \
            af[2] = (__bf16)(alo[2] * ms0.z); af[3] = (__bf16)(alo[3] * ms0.w);   \
            af[4] = (__bf16)(ahi[0] * ms1.x); af[5] = (__bf16)(ahi[1] * ms1.y);   \
            af[6] = (__bf16)(ahi[2] * ms1.z); af[7] = (__bf16)(ahi[3] * ms1.w);   \
            const bf16x8 bfr = *(const bf16x8*)(xs + (size_t)s * 1024);           \
            acc = __builtin_amdgcn_mfma_f32_16x16x32_bf16(af, bfr, acc, 0, 0, 0); \
        }                                                                         \
    }
// Per step t: issue step t+3 loads; compute step t; write step t+1 to LDS
// (implicit vmcnt waits only rg[sB], issued 2.5 steps ago); raw barrier.
#define STEP(t, sA, sB)                                                           \
    {                                                                             \
        if ((t) + 3 < NSTEP) RELOAD(sA, (t) + 3);                                 \
        __builtin_amdgcn_sched_barrier(0);                                        \
        COMPUTE(t);                                                               \
        __builtin_amdgcn_sched_barrier(0);                                        \
        if ((t) + 1 < NSTEP) {                                                    \
            DSWRITE(((t) + 1) & 1, sB);                                           \
            asm volatile("s_waitcnt lgkmcnt(0)" ::: "memory");                    \
            __builtin_amdgcn_s_barrier();                                         \
        }                                                                         \
    }

    // Prologue: fill the ring (steps 0,1,2 in flight), stage step 0 into buf0.
    RELOAD(0, 0);
    RELOAD(1, 1);
    RELOAD(2, 2);
    DSWRITE(0, 0);                       // implicit vmcnt waits rg[0] only
    asm volatile("s_waitcnt lgkmcnt(0)" ::: "memory");
    __builtin_amdgcn_s_barrier();

    STEP(0, 0, 1)
    STEP(1, 1, 2)
    STEP(2, 2, 0)
    STEP(3, 0, 1)
    STEP(4, 1, 2)
    STEP(5, 2, 0)
    STEP(6, 0, 1)
    STEP(7, 1, 2)
#undef RELOAD
#undef DSWRITE
#undef COMPUTE
#undef STEP

    // C/D: lane holds D[row=g16*4+i][col=l15]; row = o-in-tile, col = b-in-tile
    const int bg = bh * 16 + l15;                 // global b
    const float yv = y[bg * G + g];
    float* op = out + bg * (D * O) + d * O + oh * 16;
    #pragma unroll
    for (int i = 0; i < 4; ++i)
        unsafeAtomicAdd(op + g16 * 4 + i, yv * acc[i]);
}

extern "C" void kernel_launch(void* const* d_in, const int* in_sizes, int n_in,
                              void* d_out, int out_size, void* d_ws, size_t ws_size,
                              hipStream_t stream) {
    const float* x    = (const float*)d_in[0];
    const float* y    = (const float*)d_in[1];
    const float* w    = (const float*)d_in[2];
    const float* bias = (const float*)d_in[3];
    const float* mask = (const float*)d_in[4];
    float* out = (float*)d_out;

    __bf16* xbp = (__bf16*)d_ws;

    prep_and_init<<<192, 256, 0, stream>>>(x, bias, xbp, out);
    gemm_main<<<dim3(D, G, 4), 128, 0, stream>>>(w, xbp, mask, y, out);
}